// Round 11
// baseline (284.920 us; speedup 1.0000x reference)
//
#include <hip/hip_runtime.h>
#include <hip/hip_bf16.h>
#include <climits>
#include <cstdint>
#include <cfloat>

#define NROWS   524288
#define KDIM    128
#define NGRAPH  64
#define NSTROKE 8192
#define EPSF    1e-5f

typedef __bf16 bf16x8 __attribute__((ext_vector_type(8)));
typedef float  f32x4  __attribute__((ext_vector_type(4)));

// ws layout (bytes)
#define WT_OFF    0                         // ushort bf16 Wt[256][128] (col-major)
#define CSUM_OFF  65536                     // float[256]
#define CSQ_OFF   66560                     // float[256]
#define ST_OFF    67584                     // int [8192][128] stroke max (int-key)
#define GT_OFF    (ST_OFF + NSTROKE*KDIM*4) // int [64][128] graph max (int-key)

__device__ __forceinline__ unsigned short f2bf(float f) {
  unsigned int u = __float_as_uint(f);
  u += 0x7fffu + ((u >> 16) & 1u);   // RNE
  return (unsigned short)(u >> 16);
}
// order-preserving float<->int key (for atomicMax)
__device__ __forceinline__ int fkey(float f) {
  int b = __float_as_int(f);
  return b >= 0 ? b : (b ^ 0x7fffffff);
}
__device__ __forceinline__ float fdec(int k) {
  int b = k >= 0 ? k : (k ^ 0x7fffffff);
  return __int_as_float(b);
}
__device__ __forceinline__ bf16x8 cvt8(f32x4 a, f32x4 b) {
  bf16x8 r;
  r[0] = (__bf16)a[0]; r[1] = (__bf16)a[1]; r[2] = (__bf16)a[2]; r[3] = (__bf16)a[3];
  r[4] = (__bf16)b[0]; r[5] = (__bf16)b[1]; r[6] = (__bf16)b[2]; r[7] = (__bf16)b[3];
  return r;
}

// ---------------- init: weights -> bf16 col-major; clear sums + max tables ----
__global__ void k_init(const float* __restrict__ Wmax, const float* __restrict__ Wsk,
                       unsigned char* __restrict__ ws) {
  unsigned short* wt = (unsigned short*)(ws + WT_OFF);
  float* csum = (float*)(ws + CSUM_OFF);
  float* csq  = (float*)(ws + CSQ_OFF);
  int* st = (int*)(ws + ST_OFF);
  int* gt = (int*)(ws + GT_OFF);
  int i = blockIdx.x * blockDim.x + threadIdx.x;
  const int total = NSTROKE * KDIM;   // 1048576
  for (; i < total; i += gridDim.x * blockDim.x) {
    st[i] = INT_MIN;
    if (i < NGRAPH * KDIM) gt[i] = INT_MIN;
    if (i < 256) { csum[i] = 0.f; csq[i] = 0.f; }
    if (i < 256 * KDIM) {
      int c = i / KDIM, k = i % KDIM;
      float w = (c < 128) ? Wsk[k * 128 + c] : Wmax[k * 128 + (c - 128)];
      wt[i] = f2bf(w);   // wt[c][k]
    }
  }
}

// ---------------- pass1: WAVE-INDEPENDENT fused GEMM + sums + seg max ----------
// R11: no LDS, no barriers. Each wave loads its A-fragments directly from
// global in fragment layout (per load instr: 16 rows x 128 contiguous B) and
// converts fp32->bf16 in-register. The 4 waves of a block read the same tile
// through L2 (x lines reused 4x). Waves drift and retire independently —
// latency is hidden by TLP instead of being re-exposed at per-tile barriers.
// Epilogue (acc-direct segment max + BN sums) is R9-exact.
__global__ __launch_bounds__(256) void k_pass1(const float* __restrict__ x,
                                               const int* __restrict__ batch,
                                               const int* __restrict__ stroke,
                                               unsigned char* __restrict__ ws) {
  const unsigned short* wt = (const unsigned short*)(ws + WT_OFF);
  float* csum = (float*)(ws + CSUM_OFF);
  float* csq  = (float*)(ws + CSQ_OFF);
  int* st = (int*)(ws + ST_OFF);
  int* gt = (int*)(ws + GT_OFF);

  const int tid  = threadIdx.x;
  const int lane = tid & 63;
  const int wv   = tid >> 6;   // wave 0..3
  const int lr   = lane & 15;
  const int lg   = lane >> 4;

  // B fragments: lane holds Wt[col = wv*64+n*16+lr][k = ks*32+lg*8 ..+7]
  bf16x8 bfrag[4][4];
#pragma unroll
  for (int ks = 0; ks < 4; ++ks)
#pragma unroll
    for (int n = 0; n < 4; ++n) {
      int c = wv * 64 + n * 16 + lr;
      int k = ks * 32 + lg * 8;
      bfrag[ks][n] = *(const bf16x8*)(wt + c * KDIM + k);
    }

  float sumn[4] = {0.f, 0.f, 0.f, 0.f};
  float sqn[4]  = {0.f, 0.f, 0.f, 0.f};

  const bool isS = (wv < 2);
  const int* __restrict__ segp = isS ? stroke : batch;
  int* __restrict__ tab = isS ? st : gt;
  const int tcol = (isS ? wv : wv - 2) * 64;   // table column base for this wave

  int   curseg = -1;
  float runmax[4] = {-FLT_MAX, -FLT_MAX, -FLT_MAX, -FLT_MAX};

#define FLUSH()                                                               \
  if (curseg >= 0) {                                                          \
    _Pragma("unroll")                                                         \
    for (int n = 0; n < 4; ++n) {                                             \
      float f = runmax[n];                                                    \
      f = fmaxf(f, __shfl_xor(f, 16));                                        \
      f = fmaxf(f, __shfl_xor(f, 32));                                        \
      if (lg == 0) atomicMax(&tab[curseg * KDIM + tcol + n * 16 + lr], fkey(f)); \
    }                                                                         \
  }

  const int brow = blockIdx.x * 256;   // 4 tiles x 64 rows per block

  for (int ti = 0; ti < 4; ++ti) {
    const int row0 = brow + ti * 64;
    int segv = segp[row0 + lane];   // coalesced; L2-hot

    // ---- MFMA: A-fragments straight from global (fp32 -> bf16 in-reg) ----
    f32x4 acc[4][4];
#pragma unroll
    for (int m = 0; m < 4; ++m)
#pragma unroll
      for (int n = 0; n < 4; ++n) { f32x4 z = {0.f, 0.f, 0.f, 0.f}; acc[m][n] = z; }

#pragma unroll
    for (int ks = 0; ks < 4; ++ks) {
      f32x4 raw0[4], raw1[4];
#pragma unroll
      for (int m = 0; m < 4; ++m) {
        const float* p = x + (size_t)(row0 + m * 16 + lr) * KDIM + ks * 32 + lg * 8;
        raw0[m] = *(const f32x4*)p;
        raw1[m] = *(const f32x4*)(p + 4);
      }
      bf16x8 af[4];
#pragma unroll
      for (int m = 0; m < 4; ++m) af[m] = cvt8(raw0[m], raw1[m]);
#pragma unroll
      for (int m = 0; m < 4; ++m)
#pragma unroll
        for (int n = 0; n < 4; ++n)
          acc[m][n] = __builtin_amdgcn_mfma_f32_16x16x32_bf16(af[m], bfrag[ks][n], acc[m][n], 0, 0, 0);
    }

    // ---- column sums/sumsq + tile col-max straight from accumulators ----
    float tm[4];
#pragma unroll
    for (int n = 0; n < 4; ++n) {
      float s = 0.f, q = 0.f, t = -FLT_MAX;
#pragma unroll
      for (int m = 0; m < 4; ++m)
#pragma unroll
        for (int rg = 0; rg < 4; ++rg) {
          float v = acc[m][n][rg];
          s += v; q = fmaf(v, v, q); t = fmaxf(t, v);
        }
      sumn[n] += s; sqn[n] += q; tm[n] = t;
    }

    // ---- acc-direct segment max (R9-exact) ----
    {
      int pv = __shfl_up(segv, 1);
      unsigned long long mask = __ballot(lane > 0 && pv != segv);
      if (mask == 0ull) {
        int seg0 = __shfl(segv, 0);
        if (seg0 == curseg) {
#pragma unroll
          for (int n = 0; n < 4; ++n) runmax[n] = fmaxf(runmax[n], tm[n]);
        } else {
          FLUSH();
          curseg = seg0;
#pragma unroll
          for (int n = 0; n < 4; ++n) runmax[n] = tm[n];
        }
      } else {
        unsigned long long rem = mask;
        int a = 0;
        while (true) {
          int b = rem ? (int)__builtin_ctzll(rem) : 64;
          int segr = __shfl(segv, a);
          float rm[4] = {-FLT_MAX, -FLT_MAX, -FLT_MAX, -FLT_MAX};
#pragma unroll
          for (int m = 0; m < 4; ++m)
#pragma unroll
            for (int rg = 0; rg < 4; ++rg) {
              int pos = m * 16 + lg * 4 + rg;
              bool in = (pos >= a) && (pos < b);
#pragma unroll
              for (int n = 0; n < 4; ++n)
                rm[n] = in ? fmaxf(rm[n], acc[m][n][rg]) : rm[n];
            }
          if (a == 0 && segr == curseg) {
#pragma unroll
            for (int n = 0; n < 4; ++n) runmax[n] = fmaxf(runmax[n], rm[n]);
          } else {
            FLUSH();
            curseg = segr;
#pragma unroll
            for (int n = 0; n < 4; ++n) runmax[n] = rm[n];
          }
          if (b >= 64) break;
          rem &= rem - 1; a = b;
        }
      }
    }
  }

  FLUSH();   // final carried run

  // ---- finalize sums: reduce over the 4 k-group lanes, 1 atomic per column ----
#pragma unroll
  for (int n = 0; n < 4; ++n) {
    sumn[n] += __shfl_xor(sumn[n], 16);
    sumn[n] += __shfl_xor(sumn[n], 32);
    sqn[n]  += __shfl_xor(sqn[n], 16);
    sqn[n]  += __shfl_xor(sqn[n], 32);
  }
  float s = 0.f, q = 0.f;
#pragma unroll
  for (int n = 0; n < 4; ++n) if (n == lg) { s = sumn[n]; q = sqn[n]; }  // static select
  atomicAdd(&csum[tid], s);
  atomicAdd(&csq[tid], q);
#undef FLUSH
}

// ---------------- out: gather + BN(affine)+ReLU on the fly + stream write ------
// (R2-exact)
__global__ __launch_bounds__(256) void k_out(const int* __restrict__ batch,
                                             const int* __restrict__ stroke,
                                             const float* __restrict__ g_max,
                                             const float* __restrict__ be_max,
                                             const float* __restrict__ g_sk,
                                             const float* __restrict__ be_sk,
                                             const unsigned char* __restrict__ ws,
                                             float* __restrict__ out) {
  const float* csum = (const float*)(ws + CSUM_OFF);
  const float* csq  = (const float*)(ws + CSQ_OFF);
  const int* st = (const int*)(ws + ST_OFF);
  const int* gt = (const int*)(ws + GT_OFF);

  const int lane = threadIdx.x & 63;
  const int wvid = blockIdx.x * 4 + (threadIdx.x >> 6);
  const int row0 = wvid * 64;
  const bool isS = lane < 32;
  const int  cg  = (isS ? lane : lane - 32) * 4;
  const int* tab  = isS ? st : gt;
  const int* idxp = isS ? stroke : batch;
  const float* gv = isS ? g_sk : g_max;
  const float* bv = isS ? be_sk : be_max;

  const float invN = 1.0f / (float)NROWS;
  f32x4 mu, sc, bb;
#pragma unroll
  for (int j = 0; j < 4; ++j) {
    int cc = (isS ? 0 : 128) + cg + j;
    float m  = csum[cc] * invN;
    float vr = csq[cc] * invN - m * m;
    mu[j] = m;
    sc[j] = gv[cg + j] * rsqrtf(vr + EPSF);
    bb[j] = bv[cg + j];
  }

  f32x4* out4 = (f32x4*)out;
#pragma unroll 4
  for (int r = 0; r < 64; ++r) {
    int row = row0 + r;
    int seg = idxp[row];
    const int4 k4 = *(const int4*)(tab + (size_t)seg * KDIM + cg);
    f32x4 v;
    v[0] = fdec(k4.x); v[1] = fdec(k4.y); v[2] = fdec(k4.z); v[3] = fdec(k4.w);
#pragma unroll
    for (int j = 0; j < 4; ++j) v[j] = fmaxf(0.f, (v[j] - mu[j]) * sc[j] + bb[j]);
    __builtin_nontemporal_store(v, &out4[(size_t)row * 64 + lane]);
  }
}

extern "C" void kernel_launch(void* const* d_in, const int* in_sizes, int n_in,
                              void* d_out, int out_size, void* d_ws, size_t ws_size,
                              hipStream_t stream) {
  const float* x      = (const float*)d_in[0];
  const int*   batch  = (const int*)d_in[1];
  const int*   stroke = (const int*)d_in[2];
  const float* Wmax   = (const float*)d_in[3];
  const float* g_max  = (const float*)d_in[5];
  const float* be_max = (const float*)d_in[6];
  const float* Wsk    = (const float*)d_in[7];
  const float* g_sk   = (const float*)d_in[9];
  const float* be_sk  = (const float*)d_in[10];
  unsigned char* ws = (unsigned char*)d_ws;
  float* out = (float*)d_out;

  k_init <<<2048, 512, 0, stream>>>(Wmax, Wsk, ws);
  k_pass1<<<2048, 256, 0, stream>>>(x, batch, stroke, ws);
  k_out  <<<2048, 256, 0, stream>>>(batch, stroke, g_max, be_max, g_sk, be_sk, ws, out);
}